// Round 7
// baseline (943.366 us; speedup 1.0000x reference)
//
#include <hip/hip_runtime.h>

typedef __attribute__((ext_vector_type(8))) short short8;
typedef __attribute__((ext_vector_type(4))) float f32x4;

#define NSTEPS 16

__device__ __forceinline__ unsigned short bf16rne(float f) {
  unsigned int u = __float_as_uint(f);
  u += 0x7FFFu + ((u >> 16) & 1u);
  return (unsigned short)(u >> 16);
}

// Single hardware instr (v_cvt_pk_bf16_f32), RNE. No builtin on gfx950.
__device__ __forceinline__ unsigned int pk2(float a, float b) {
  unsigned int r;
  asm("v_cvt_pk_bf16_f32 %0, %1, %2" : "=v"(r) : "v"(a), "v"(b));
  return r;
}

__device__ __forceinline__ float bflo(unsigned int w) { return __uint_as_float(w << 16); }
__device__ __forceinline__ float bfhi(unsigned int w) { return __uint_as_float(w & 0xFFFF0000u); }

__device__ __forceinline__ float tanh_fast(float x) {
  // tanh(x) = 1 - 2/(e^{2x}+1); e->inf => 1, e->0 => -1 (no clamp needed)
  float e = __builtin_amdgcn_exp2f(x * 2.8853900817779268f);
  return __builtin_fmaf(-2.0f, __builtin_amdgcn_rcpf(e + 1.0f), 1.0f);
}

// ---- Explicit AGPR residency for persistent weight fragments ----------------
// Rounds 3/4/6 proved the compiler will NOT keep the 128 regs of weight frags
// out of the arch-VGPR file on its own (scratch spill, 20-30 MB/dispatch).
// Round 5 proved opaque-asm MFMA corrupts results (lost MFMA hazard nops).
// This scheme forces the register class at every def/use with plain VALU
// moves (v_accvgpr_write/read — normal dependencies, no MFMA hazards), while
// the MFMA itself stays a builtin so the compiler keeps hazard ownership.
struct afrag { unsigned int x, y, z, w; };
union frag_cast { short8 s; unsigned int u[4]; };

__device__ __forceinline__ afrag to_agpr(short8 v) {
  frag_cast c; c.s = v;
  afrag a;
  asm("v_accvgpr_write_b32 %0, %4\n\t"
      "v_accvgpr_write_b32 %1, %5\n\t"
      "v_accvgpr_write_b32 %2, %6\n\t"
      "v_accvgpr_write_b32 %3, %7"
      : "=a"(a.x), "=a"(a.y), "=a"(a.z), "=a"(a.w)
      : "v"(c.u[0]), "v"(c.u[1]), "v"(c.u[2]), "v"(c.u[3]));
  return a;
}

__device__ __forceinline__ short8 from_agpr(afrag a) {
  frag_cast c;
  asm("v_accvgpr_read_b32 %0, %4\n\t"
      "v_accvgpr_read_b32 %1, %5\n\t"
      "v_accvgpr_read_b32 %2, %6\n\t"
      "v_accvgpr_read_b32 %3, %7"
      : "=v"(c.u[0]), "=v"(c.u[1]), "=v"(c.u[2]), "=v"(c.u[3])
      : "a"(a.x), "a"(a.y), "a"(a.z), "a"(a.w));
  return c.s;
}

// Pre-shuffle fp32 weights -> bf16 MFMA fragments (B-frag of W == A-frag of W^T).
// lane holds W[k = 32*ks + 8*(lane>>4) + j][c = 16*t + (lane&15)], j=0..7
__global__ void ffjord_setup(const float* __restrict__ W1a, const float* __restrict__ W2a,
                             const float* __restrict__ W3a, const float* __restrict__ W1b,
                             const float* __restrict__ W2b, const float* __restrict__ W3b,
                             unsigned short* __restrict__ ws) {
  int gid = blockIdx.x * blockDim.x + threadIdx.x;   // 0..24575
  int bij = gid / 12288;
  int r = gid - bij * 12288;
  const float* W1 = bij ? W1b : W1a;
  const float* W2 = bij ? W2b : W2a;
  const float* W3 = bij ? W3b : W3a;
  unsigned short* o = ws + bij * 98304;
  const float* src;
  int kstride;
  if (r < 2048) {                 // W1f
    int lane = r & 63, nt = (r >> 6) & 15, ks = r >> 10;
    int k0 = ks * 32 + (lane >> 4) * 8, n = nt * 16 + (lane & 15);
    src = W1 + k0 * 256 + n; kstride = 256; o += r * 8;
  } else if (r < 10240) {         // W2f
    int rr = r - 2048;
    int lane = rr & 63, nt = (rr >> 6) & 15, ks = rr >> 10;
    int k0 = ks * 32 + (lane >> 4) * 8, n = nt * 16 + (lane & 15);
    src = W2 + k0 * 256 + n; kstride = 256; o += 16384 + rr * 8;
  } else {                        // W3f (unused by main now; kept for layout stability)
    int rr = r - 10240;
    int lane = rr & 63, nt = (rr >> 6) & 3, ks = rr >> 8;
    int k0 = ks * 32 + (lane >> 4) * 8, n = nt * 16 + (lane & 15);
    src = W3 + k0 * 64 + n; kstride = 64; o += 81920 + rr * 8;
  }
  #pragma unroll
  for (int j = 0; j < 8; j++) o[j] = bf16rne(src[j * kstride]);
}

// Composed-operator setup: M2[a][c] = sum_d W3[a][d]*W1[d][c]  (256x256, fp32
// accumulate, one bf16 rounding) emitted as W2-style MFMA frags at ws+196608
// (+bij*65536); cb3[c] = sum_d W1[d][c]*b3[d] as f32 at ws+327680.
__global__ void ffjord_setup2(const float* __restrict__ W1a, const float* __restrict__ W3a,
                              const float* __restrict__ b3a, const float* __restrict__ W1b,
                              const float* __restrict__ W3b, const float* __restrict__ b3b,
                              unsigned short* __restrict__ ws) {
  int bid = blockIdx.x;
  int tid = threadIdx.x;
  if (bid < 64) {
    int gid = bid * 4 + (tid >> 6);  // 0..255 = 2 bij x 8 ks x 16 t
    int bij = gid >> 7;
    int rem = gid & 127;
    int ks = rem >> 4;
    int t = rem & 15;
    int lane = tid & 63;
    const float* W1 = bij ? W1b : W1a;
    const float* W3 = bij ? W3b : W3a;
    int c = t * 16 + (lane & 15);
    int kb = ks * 32 + (lane >> 4) * 8;
    float acc[8];
    #pragma unroll
    for (int j = 0; j < 8; j++) acc[j] = 0.f;
    for (int d = 0; d < 64; d++) {
      float w1d = W1[d * 256 + c];
      #pragma unroll
      for (int j = 0; j < 8; j++)
        acc[j] = __builtin_fmaf(W3[(kb + j) * 64 + d], w1d, acc[j]);
    }
    unsigned short* o = ws + 196608 + bij * 65536 + ((ks * 16 + t) * 64 + lane) * 8;
    #pragma unroll
    for (int j = 0; j < 8; j++) o[j] = bf16rne(acc[j]);
  } else {
    // cb3: 512 values (2 bij x 256)
    for (int v = tid; v < 512; v += 256) {
      int bij = v >> 8, c = v & 255;
      const float* W1 = bij ? W1b : W1a;
      const float* b3 = bij ? b3b : b3a;
      float a = 0.f;
      for (int d = 0; d < 64; d++) a = __builtin_fmaf(W1[d * 256 + c], b3[d], a);
      ((float*)(ws + 327680))[v] = a;
    }
  }
}

// R[bij] = (W1s W1s^T)^{-1} W1s (64x256 f32) at ws+328704 (+bij*16384 floats).
// G = W1s W1s^T is ~3.9*I +- 0.25 noise (cond ~9): no-pivot Gauss-Jordan in
// fp32 is safe. y = R * uy recovers the state from its W1^T-projection.
__global__ void ffjord_setup3(const float* __restrict__ W1a, const float* __restrict__ W1b,
                              unsigned short* __restrict__ ws) {
  const float* W1 = blockIdx.x ? W1b : W1a;
  float* Rout = (float*)(ws + 328704) + blockIdx.x * 16384;
  __shared__ float G[64][65];
  __shared__ float Inv[64][65];
  int tid = threadIdx.x;  // 1024
  for (int e = tid; e < 4096; e += 1024) {
    int i = e >> 6, j = e & 63;
    float a = 0.f;
    for (int c = 0; c < 256; c += 4) {
      f32x4 ri = *(const f32x4*)(W1 + i * 256 + c);
      f32x4 rj = *(const f32x4*)(W1 + j * 256 + c);
      a += ri[0] * rj[0] + ri[1] * rj[1] + ri[2] * rj[2] + ri[3] * rj[3];
    }
    G[i][j] = a;
    Inv[i][j] = (i == j) ? 1.f : 0.f;
  }
  __syncthreads();
  for (int p = 0; p < 64; p++) {
    float rp = 1.0f / G[p][p];
    __syncthreads();            // everyone has rp before row p is scaled
    if (tid < 128) {
      int j = tid & 63;
      if (tid < 64) G[p][j] *= rp;
      else Inv[p][j] *= rp;
    }
    __syncthreads();
    for (int e = tid; e < 8192; e += 1024) {
      int i = e >> 7, j = e & 127;
      if (i != p) {
        float f = G[i][p];      // col p is skipped below -> no write race
        if (j < 64) {
          if (j != p) G[i][j] = __builtin_fmaf(-f, G[p][j], G[i][j]);
        } else {
          Inv[i][j - 64] = __builtin_fmaf(-f, Inv[p][j - 64], Inv[i][j - 64]);
        }
      }
    }
    __syncthreads();
  }
  // R = Inv * W1s
  for (int e = tid; e < 16384; e += 1024) {
    int d = e >> 8, c = e & 255;
    float a = 0.f;
    for (int j = 0; j < 64; j++) a = __builtin_fmaf(Inv[d][j], W1[j * 256 + c], a);
    Rout[d * 256 + c] = a;
  }
}

// 2-phase stage loop via operator composition, k-side eliminated:
//   state = uy (= W1s^T y, per-wave 32 dims, f32 registers).
//   Phase A: h2 = tanh(W2^T h1 + b2)      [16 MFMA/wave, h1A -> h2A]
//   Phase B: u  = M2^T h2 + cb3           [16 MFMA/wave, wave-local]
//            h1_{s+1} = tanh(uy + h*sum a_j u_j + b1 + t*w1t) -> h1A
//   Persistent weight frags (w2/m2, 128 regs) in AGPRs via EXPLICIT
//   v_accvgpr_write at load + v_accvgpr_read at use (8 copies/phase/wave,
//   shared across both tiles). Arch-VGPR live set ~90; AGPR 128; no spill.
//   u-history packed bf16; trajectory uy accumulates f32. y recovered at
//   bijector end via y = R*uy (pinv). 2 barriers/stage, no wave divergence.
__global__ __launch_bounds__(512, 2) void ffjord_main(
    const float* __restrict__ x, float* __restrict__ out,
    const unsigned short* __restrict__ ws,
    const float* __restrict__ W1a, const float* __restrict__ b1a,
    const float* __restrict__ b2a, const float* __restrict__ b3a,
    const float* __restrict__ W1b, const float* __restrict__ b1b,
    const float* __restrict__ b2b, const float* __restrict__ b3b) {
  __shared__ __align__(16) unsigned short zA[1088];    // y as B-frags (transitions)
  __shared__ __align__(16) unsigned short h1A[4096];   // [g8][row16][j8]
  __shared__ __align__(16) unsigned short h2A[4096];
  __shared__ __align__(16) f32x4 cbuf[2][64];          // [0]=b2, [1]=cb3 broadcast
  __shared__ __align__(16) float uyS[16][260];         // extraction (padded)
  __shared__ __align__(16) float yS[16][68];           // extracted y (padded)

  const int tid = threadIdx.x;
  const int wave = tid >> 6;        // 0..7
  const int lane = tid & 63;
  const int cl = lane & 15;
  const int qd = lane >> 4;
  const int row0 = blockIdx.x * 16;

  const int tc0 = wave * 2, tc1 = tc0 + 1;
  const int c0 = wave * 32 + qd * 4;                   // tile-0 dim base
  const int hoff = wave * 512 + (qd >> 1) * 128 + cl * 8 + 4 * (qd & 1);
  const int zrb = qd * 136 + cl * 8;
  const int w3i = wave & 3;
  const int dl3 = w3i * 16 + qd * 4;
  const int zw = (2 * w3i + (qd >> 1)) * 136 + cl * 8 + 4 * (qd & 1);
  const int cidx = wave * 8 + qd * 2;

  const float hstep = 1.0f / 16.0f;

  f32x4 yc;           // y slice at transitions (waves 0-3)

  const float A2[5][5] = {
      {1.f / 5.f, 0.f, 0.f, 0.f, 0.f},
      {3.f / 40.f, 9.f / 40.f, 0.f, 0.f, 0.f},
      {44.f / 45.f, -56.f / 15.f, 32.f / 9.f, 0.f, 0.f},
      {19372.f / 6561.f, -25360.f / 2187.f, 64448.f / 6561.f, -212.f / 729.f, 0.f},
      {9017.f / 3168.f, -355.f / 33.f, 46732.f / 5247.f, 49.f / 176.f, -5103.f / 18656.f}};
  const float CT[6] = {0.0f, 0.2f, 0.3f, 0.8f, 8.0f / 9.0f, 1.0f};
  const float BW0 = 35.f / 384.f, BW2 = 500.f / 1113.f, BW3 = 125.f / 192.f,
              BW4 = -2187.f / 6784.f, BW5 = 11.f / 84.f;
  const float HBW[6] = {hstep * BW0, 0.f, hstep * BW2, hstep * BW3,
                        hstep * BW4, hstep * BW5};

  for (int bij = 0; bij < 2; bij++) {
    const unsigned short* wsb = ws + bij * 98304;
    const float* W1 = bij ? W1b : W1a;
    const float* b1 = bij ? b1b : b1a;
    const float* b2 = bij ? b2b : b2a;

    f32x4 b1c0 = *(const f32x4*)(b1 + c0);
    f32x4 b1c1 = *(const f32x4*)(b1 + c0 + 16);
    f32x4 w1t0 = *(const f32x4*)(W1 + 64 * 256 + c0);
    f32x4 w1t1 = *(const f32x4*)(W1 + 64 * 256 + c0 + 16);

    // broadcast constants -> tiny LDS table (saves 16 VGPR)
    if (cl == 0) {
      cbuf[0][cidx] = *(const f32x4*)(b2 + c0);
      cbuf[0][cidx + 1] = *(const f32x4*)(b2 + c0 + 16);
      cbuf[1][cidx] = *(const f32x4*)((const float*)(ws + 327680) + bij * 256 + c0);
      cbuf[1][cidx + 1] = *(const f32x4*)((const float*)(ws + 327680) + bij * 256 + c0 + 16);
    }

    // persistent W2 and M2 fragments -> AGPR file (explicit accvgpr_write)
    const short8* w2p = (const short8*)(wsb + 16384);
    const short8* mp = (const short8*)(ws + 196608 + bij * 65536);
    afrag aw20[8], aw21[8], am0[8], am1[8];
    #pragma unroll
    for (int ks = 0; ks < 8; ks++) {
      aw20[ks] = to_agpr(w2p[(ks * 16 + tc0) * 64 + lane]);
      aw21[ks] = to_agpr(w2p[(ks * 16 + tc1) * 64 + lane]);
      am0[ks] = to_agpr(mp[(ks * 16 + tc0) * 64 + lane]);
      am1[ks] = to_agpr(mp[(ks * 16 + tc1) * 64 + lane]);
    }

    // ---- bijector entry: publish y as B-frags, uy = W1s^T y, h1_0 = tanh(uy+b1)
    if (wave < 4) {
      if (bij == 0) yc = *(const f32x4*)(x + (row0 + cl) * 64 + dl3);
      uint2 pv;
      pv.x = pk2(yc[0], yc[1]);
      pv.y = pk2(yc[2], yc[3]);
      *(uint2*)(zA + zw) = pv;
    }
    __syncthreads();

    f32x4 uy0, uy1;
    {
      const short8* w1p = (const short8*)wsb;
      short8 wA0 = w1p[(0 * 16 + tc0) * 64 + lane];
      short8 wA1 = w1p[(1 * 16 + tc0) * 64 + lane];
      short8 wB0 = w1p[(0 * 16 + tc1) * 64 + lane];
      short8 wB1 = w1p[(1 * 16 + tc1) * 64 + lane];
      short8 a0 = *(const short8*)(zA + zrb);
      short8 a1 = *(const short8*)(zA + zrb + 544);
      f32x4 r0 = {0.f, 0.f, 0.f, 0.f}, r1 = {0.f, 0.f, 0.f, 0.f};
      r0 = __builtin_amdgcn_mfma_f32_16x16x32_bf16(wA0, a0, r0, 0, 0, 0);
      r1 = __builtin_amdgcn_mfma_f32_16x16x32_bf16(wB0, a0, r1, 0, 0, 0);
      r0 = __builtin_amdgcn_mfma_f32_16x16x32_bf16(wA1, a1, r0, 0, 0, 0);
      r1 = __builtin_amdgcn_mfma_f32_16x16x32_bf16(wB1, a1, r1, 0, 0, 0);
      uy0 = r0;
      uy1 = r1;
      uint2 pv0, pv1;   // t=0 at bijector entry
      pv0.x = pk2(tanh_fast(r0[0] + b1c0[0]), tanh_fast(r0[1] + b1c0[1]));
      pv0.y = pk2(tanh_fast(r0[2] + b1c0[2]), tanh_fast(r0[3] + b1c0[3]));
      pv1.x = pk2(tanh_fast(r1[0] + b1c1[0]), tanh_fast(r1[1] + b1c1[1]));
      pv1.y = pk2(tanh_fast(r1[2] + b1c1[2]), tanh_fast(r1[3] + b1c1[3]));
      *(uint2*)(h1A + hoff) = pv0;
      *(uint2*)(h1A + hoff + 256) = pv1;
    }
    __syncthreads();

    for (int step = 0; step < NSTEPS; step++) {
      float stepf = (float)step;
      uint2 uhp0[5], uhp1[5];                       // bf16 u-history (static idx)
      f32x4 uyA0 = {0.f, 0.f, 0.f, 0.f};            // f32 sum(b_s * u_s)
      f32x4 uyA1 = {0.f, 0.f, 0.f, 0.f};
      #pragma unroll
      for (int s = 0; s < 6; s++) {
        // ---- phase A: h2 = tanh(W2^T h1 + b2), K=256, 2 tiles/wave
        {
          f32x4 aA0 = cbuf[0][cidx];
          f32x4 aA1 = cbuf[0][cidx + 1];
          f32x4 aB0 = {0.f, 0.f, 0.f, 0.f}, aB1 = {0.f, 0.f, 0.f, 0.f};
          #pragma unroll
          for (int ks = 0; ks < 4; ks++) {
            short8 hb = ((const short8*)h1A)[ks * 64 + lane];
            short8 w0 = from_agpr(aw20[ks]);
            short8 w1 = from_agpr(aw21[ks]);
            aA0 = __builtin_amdgcn_mfma_f32_16x16x32_bf16(w0, hb, aA0, 0, 0, 0);
            aA1 = __builtin_amdgcn_mfma_f32_16x16x32_bf16(w1, hb, aA1, 0, 0, 0);
          }
          #pragma unroll
          for (int ks = 4; ks < 8; ks++) {
            short8 hb = ((const short8*)h1A)[ks * 64 + lane];
            short8 w0 = from_agpr(aw20[ks]);
            short8 w1 = from_agpr(aw21[ks]);
            aB0 = __builtin_amdgcn_mfma_f32_16x16x32_bf16(w0, hb, aB0, 0, 0, 0);
            aB1 = __builtin_amdgcn_mfma_f32_16x16x32_bf16(w1, hb, aB1, 0, 0, 0);
          }
          uint2 pv0, pv1;
          pv0.x = pk2(tanh_fast(aA0[0] + aB0[0]), tanh_fast(aA0[1] + aB0[1]));
          pv0.y = pk2(tanh_fast(aA0[2] + aB0[2]), tanh_fast(aA0[3] + aB0[3]));
          pv1.x = pk2(tanh_fast(aA1[0] + aB1[0]), tanh_fast(aA1[1] + aB1[1]));
          pv1.y = pk2(tanh_fast(aA1[2] + aB1[2]), tanh_fast(aA1[3] + aB1[3]));
          *(uint2*)(h2A + hoff) = pv0;
          *(uint2*)(h2A + hoff + 256) = pv1;
        }
        __syncthreads();

        // ---- phase B: u_s = M2^T h2 + cb3 (wave-local), RK combine, tanh -> h1A
        {
          f32x4 uA0 = cbuf[1][cidx];
          f32x4 uA1 = cbuf[1][cidx + 1];
          f32x4 uB0 = {0.f, 0.f, 0.f, 0.f}, uB1 = {0.f, 0.f, 0.f, 0.f};
          #pragma unroll
          for (int ks = 0; ks < 4; ks++) {
            short8 hb = ((const short8*)h2A)[ks * 64 + lane];
            short8 m0 = from_agpr(am0[ks]);
            short8 m1 = from_agpr(am1[ks]);
            uA0 = __builtin_amdgcn_mfma_f32_16x16x32_bf16(m0, hb, uA0, 0, 0, 0);
            uA1 = __builtin_amdgcn_mfma_f32_16x16x32_bf16(m1, hb, uA1, 0, 0, 0);
          }
          #pragma unroll
          for (int ks = 4; ks < 8; ks++) {
            short8 hb = ((const short8*)h2A)[ks * 64 + lane];
            short8 m0 = from_agpr(am0[ks]);
            short8 m1 = from_agpr(am1[ks]);
            uB0 = __builtin_amdgcn_mfma_f32_16x16x32_bf16(m0, hb, uB0, 0, 0, 0);
            uB1 = __builtin_amdgcn_mfma_f32_16x16x32_bf16(m1, hb, uB1, 0, 0, 0);
          }
          f32x4 uc0, uc1;
          #pragma unroll
          for (int r = 0; r < 4; r++) {
            uc0[r] = uA0[r] + uB0[r];
            uc1[r] = uA1[r] + uB1[r];
          }
          if (s != 1) {   // BW1 = 0
            #pragma unroll
            for (int r = 0; r < 4; r++) {
              uyA0[r] = __builtin_fmaf(HBW[s], uc0[r], uyA0[r]);
              uyA1[r] = __builtin_fmaf(HBW[s], uc1[r], uyA1[r]);
            }
          }

          float tnext = (s < 5) ? (stepf + CT[s + 1]) * hstep
                                : (stepf + 1.0f) * hstep;
          f32x4 p0, p1;
          if (s < 5) {
            uhp0[s].x = pk2(uc0[0], uc0[1]);
            uhp0[s].y = pk2(uc0[2], uc0[3]);
            uhp1[s].x = pk2(uc1[0], uc1[1]);
            uhp1[s].y = pk2(uc1[2], uc1[3]);
            float ad = hstep * A2[s][s];
            #pragma unroll
            for (int r = 0; r < 4; r++) {
              p0[r] = __builtin_fmaf(tnext, w1t0[r], b1c0[r]) + uy0[r];
              p1[r] = __builtin_fmaf(tnext, w1t1[r], b1c1[r]) + uy1[r];
              p0[r] = __builtin_fmaf(ad, uc0[r], p0[r]);
              p1[r] = __builtin_fmaf(ad, uc1[r], p1[r]);
            }
            #pragma unroll
            for (int j = 0; j < 4; j++)
              if (j < s) {
                float a = hstep * A2[s][j];
                p0[0] = __builtin_fmaf(a, bflo(uhp0[j].x), p0[0]);
                p0[1] = __builtin_fmaf(a, bfhi(uhp0[j].x), p0[1]);
                p0[2] = __builtin_fmaf(a, bflo(uhp0[j].y), p0[2]);
                p0[3] = __builtin_fmaf(a, bfhi(uhp0[j].y), p0[3]);
                p1[0] = __builtin_fmaf(a, bflo(uhp1[j].x), p1[0]);
                p1[1] = __builtin_fmaf(a, bfhi(uhp1[j].x), p1[1]);
                p1[2] = __builtin_fmaf(a, bflo(uhp1[j].y), p1[2]);
                p1[3] = __builtin_fmaf(a, bfhi(uhp1[j].y), p1[3]);
              }
          } else {
            #pragma unroll
            for (int r = 0; r < 4; r++) {
              uy0[r] += uyA0[r];
              uy1[r] += uyA1[r];
              p0[r] = __builtin_fmaf(tnext, w1t0[r], b1c0[r]) + uy0[r];
              p1[r] = __builtin_fmaf(tnext, w1t1[r], b1c1[r]) + uy1[r];
            }
          }
          uint2 pv0, pv1;
          pv0.x = pk2(tanh_fast(p0[0]), tanh_fast(p0[1]));
          pv0.y = pk2(tanh_fast(p0[2]), tanh_fast(p0[3]));
          pv1.x = pk2(tanh_fast(p1[0]), tanh_fast(p1[1]));
          pv1.y = pk2(tanh_fast(p1[2]), tanh_fast(p1[3]));
          *(uint2*)(h1A + hoff) = pv0;
          *(uint2*)(h1A + hoff + 256) = pv1;
        }
        __syncthreads();
      } // stages
    } // steps

    // ---- end of bijector: y = R * uy (pinv extraction)
    *(f32x4*)(&uyS[cl][c0]) = uy0;
    *(f32x4*)(&uyS[cl][c0 + 16]) = uy1;
    __syncthreads();
    {
      int erow = tid & 15;
      int ed = (tid >> 4) * 2;
      const float* Rb = (const float*)(ws + 328704) + bij * 16384;
      float a0 = 0.f, a1 = 0.f;
      for (int c = 0; c < 256; c += 4) {
        f32x4 u4 = *(const f32x4*)(&uyS[erow][c]);
        f32x4 r4 = *(const f32x4*)(Rb + ed * 256 + c);
        f32x4 r5 = *(const f32x4*)(Rb + (ed + 1) * 256 + c);
        a0 += u4[0] * r4[0] + u4[1] * r4[1] + u4[2] * r4[2] + u4[3] * r4[3];
        a1 += u4[0] * r5[0] + u4[1] * r5[1] + u4[2] * r5[2] + u4[3] * r5[3];
      }
      if (bij == 0) {
        yS[erow][ed] = a0;
        yS[erow][ed + 1] = a1;
      } else {
        float2 o2;
        o2.x = a0;
        o2.y = a1;
        *(float2*)(out + (row0 + erow) * 64 + ed) = o2;
      }
    }
    __syncthreads();
    if (bij == 0 && wave < 4) yc = *(const f32x4*)(&yS[cl][dl3]);
  } // bijectors
}

extern "C" void kernel_launch(void* const* d_in, const int* in_sizes, int n_in,
                              void* d_out, int out_size, void* d_ws, size_t ws_size,
                              hipStream_t stream) {
  (void)in_sizes; (void)n_in; (void)out_size; (void)ws_size;
  const float* x   = (const float*)d_in[0];
  const float* W1a = (const float*)d_in[1];
  const float* b1a = (const float*)d_in[2];
  const float* W2a = (const float*)d_in[3];
  const float* b2a = (const float*)d_in[4];
  const float* W3a = (const float*)d_in[5];
  const float* b3a = (const float*)d_in[6];
  const float* W1b = (const float*)d_in[7];
  const float* b1b = (const float*)d_in[8];
  const float* W2b = (const float*)d_in[9];
  const float* b2b = (const float*)d_in[10];
  const float* W3b = (const float*)d_in[11];
  const float* b3b = (const float*)d_in[12];
  unsigned short* ws = (unsigned short*)d_ws;
  float* out = (float*)d_out;

  hipLaunchKernelGGL(ffjord_setup, dim3(96), dim3(256), 0, stream,
                     W1a, W2a, W3a, W1b, W2b, W3b, ws);
  hipLaunchKernelGGL(ffjord_setup2, dim3(65), dim3(256), 0, stream,
                     W1a, W3a, b3a, W1b, W3b, b3b, ws);
  hipLaunchKernelGGL(ffjord_setup3, dim3(2), dim3(1024), 0, stream,
                     W1a, W1b, ws);
  hipLaunchKernelGGL(ffjord_main, dim3(256), dim3(512), 0, stream,
                     x, out, ws, W1a, b1a, b2a, b3a, W1b, b1b, b2b, b3b);
}

// Round 8
// 380.309 us; speedup vs baseline: 2.4805x; 2.4805x over previous
//
#include <hip/hip_runtime.h>

typedef __attribute__((ext_vector_type(8))) short short8;
typedef __attribute__((ext_vector_type(4))) float f32x4;

#define NSTEPS 16

__device__ __forceinline__ unsigned short bf16rne(float f) {
  unsigned int u = __float_as_uint(f);
  u += 0x7FFFu + ((u >> 16) & 1u);
  return (unsigned short)(u >> 16);
}

// Single hardware instr (v_cvt_pk_bf16_f32), RNE. No builtin on gfx950.
__device__ __forceinline__ unsigned int pk2(float a, float b) {
  unsigned int r;
  asm("v_cvt_pk_bf16_f32 %0, %1, %2" : "=v"(r) : "v"(a), "v"(b));
  return r;
}

__device__ __forceinline__ float tanh_fast(float x) {
  // tanh(x) = 1 - 2/(e^{2x}+1); e->inf => 1, e->0 => -1 (no clamp needed)
  float e = __builtin_amdgcn_exp2f(x * 2.8853900817779268f);
  return __builtin_fmaf(-2.0f, __builtin_amdgcn_rcpf(e + 1.0f), 1.0f);
}

// Pre-shuffle fp32 weights -> bf16 MFMA fragments (B-frag of W == A-frag of W^T).
// lane holds W[k = 32*ks + 8*(lane>>4) + j][c = 16*t + (lane&15)], j=0..7
__global__ void ffjord_setup(const float* __restrict__ W1a, const float* __restrict__ W2a,
                             const float* __restrict__ W3a, const float* __restrict__ W1b,
                             const float* __restrict__ W2b, const float* __restrict__ W3b,
                             unsigned short* __restrict__ ws) {
  int gid = blockIdx.x * blockDim.x + threadIdx.x;   // 0..24575
  int bij = gid / 12288;
  int r = gid - bij * 12288;
  const float* W1 = bij ? W1b : W1a;
  const float* W2 = bij ? W2b : W2a;
  const float* W3 = bij ? W3b : W3a;
  unsigned short* o = ws + bij * 98304;
  const float* src;
  int kstride;
  if (r < 2048) {                 // W1f
    int lane = r & 63, nt = (r >> 6) & 15, ks = r >> 10;
    int k0 = ks * 32 + (lane >> 4) * 8, n = nt * 16 + (lane & 15);
    src = W1 + k0 * 256 + n; kstride = 256; o += r * 8;
  } else if (r < 10240) {         // W2f
    int rr = r - 2048;
    int lane = rr & 63, nt = (rr >> 6) & 15, ks = rr >> 10;
    int k0 = ks * 32 + (lane >> 4) * 8, n = nt * 16 + (lane & 15);
    src = W2 + k0 * 256 + n; kstride = 256; o += 16384 + rr * 8;
  } else {                        // W3f
    int rr = r - 10240;
    int lane = rr & 63, nt = (rr >> 6) & 3, ks = rr >> 8;
    int k0 = ks * 32 + (lane >> 4) * 8, n = nt * 16 + (lane & 15);
    src = W3 + k0 * 64 + n; kstride = 64; o += 81920 + rr * 8;
  }
  #pragma unroll
  for (int j = 0; j < 8; j++) o[j] = bf16rne(src[j * kstride]);
}

// 1024 threads / 16 waves, 16 batch rows per block, grid 256 (1 block/CU).
// Proven 3-phase structure (round-1 champion, 248 us) with two L3-chain cuts:
//  - W3 frags in REGISTERS on waves 0-3 (proven allocation-safe in round 2):
//    removes 16 ds_read_b128 from the L3 dependent chain + 64 KB w3s LDS.
//  - L3 MFMA as 4 chains of 2 (was 2 chains of 4): shorter dependent-latency
//    tail before the z-build that gates the next stage's L1.
// RK k-history kh[5] in registers (static indices after the stage unroll).
// 3 barriers/stage. Worst-wave VGPR ~112 < 128 -> 4 waves/SIMD.
__global__ __launch_bounds__(1024, 4) void ffjord_main(
    const float* __restrict__ x, float* __restrict__ out,
    const unsigned short* __restrict__ ws,
    const float* __restrict__ W1a, const float* __restrict__ b1a,
    const float* __restrict__ b2a, const float* __restrict__ b3a,
    const float* __restrict__ W1b, const float* __restrict__ b1b,
    const float* __restrict__ b2b, const float* __restrict__ b3b) {
  // zA: 8 groups of (16 rows x 8 j) ushorts, each group padded 256B->272B
  __shared__ __align__(16) unsigned short zA[1088];
  __shared__ __align__(16) unsigned short h1A[4096];   // [g8][row16][j8]
  __shared__ __align__(16) unsigned short h2A[4096];

  const int tid = threadIdx.x;
  const int wave = tid >> 6;        // 0..15
  const int lane = tid & 63;
  const int cl = lane & 15;
  const int qd = lane >> 4;
  const int row0 = blockIdx.x * 16;

  // L1/L2 output tile: wave w owns hidden dims [w*16, w*16+16)
  const int c0 = wave * 16 + qd * 4;
  const int hoff = (c0 >> 5) * 512 + ((c0 & 31) >> 3) * 128 + cl * 8 + (c0 & 7);
  // z A-frag read base (second frag at +544 ushorts)
  const int zrb = qd * 136 + cl * 8;
  // L3 thread coords (waves 0-3): dims dl3..dl3+3 of batch row cl
  const int w3i = wave & 3;
  const int dl3 = w3i * 16 + qd * 4;
  // z-frag write slot for those 4 dims (b64-aligned)
  const int zw = (2 * w3i + (qd >> 1)) * 136 + cl * 8 + 4 * (qd & 1);

  const float hstep = 1.0f / 16.0f;

  f32x4 yc;           // private y slice (4 dims x 1 row), waves 0-3

  // A2[s] = DOPRI a_{s+1,j} coefficients (z for stage s+1 built at stage s);
  // row s has entries j=0..s (diag = coefficient of k_s).
  const float A2[5][5] = {
      {1.f / 5.f, 0.f, 0.f, 0.f, 0.f},
      {3.f / 40.f, 9.f / 40.f, 0.f, 0.f, 0.f},
      {44.f / 45.f, -56.f / 15.f, 32.f / 9.f, 0.f, 0.f},
      {19372.f / 6561.f, -25360.f / 2187.f, 64448.f / 6561.f, -212.f / 729.f, 0.f},
      {9017.f / 3168.f, -355.f / 33.f, 46732.f / 5247.f, 49.f / 176.f, -5103.f / 18656.f}};
  const float CT[6] = {0.0f, 0.2f, 0.3f, 0.8f, 8.0f / 9.0f, 1.0f};
  const float BW0 = 35.f / 384.f, BW2 = 500.f / 1113.f, BW3 = 125.f / 192.f,
              BW4 = -2187.f / 6784.f, BW5 = 11.f / 84.f;

  for (int bij = 0; bij < 2; bij++) {
    const unsigned short* wsb = ws + bij * 98304;
    const float* W1 = bij ? W1b : W1a;
    const float* b1 = bij ? b1b : b1a;
    const float* b2 = bij ? b2b : b2a;
    const float* b3 = bij ? b3b : b3a;

    f32x4 b1c = *(const f32x4*)(b1 + c0);
    f32x4 w1t4 = *(const f32x4*)(W1 + 64 * 256 + c0);
    f32x4 b2c = *(const f32x4*)(b2 + c0);
    f32x4 b3c = *(const f32x4*)(b3 + dl3);

    // register-resident W1/W2 fragments (A-operand of W^T)
    const short8* w1p = (const short8*)wsb;
    const short8* w2p = (const short8*)(wsb + 16384);
    short8 w1f[2];
    #pragma unroll
    for (int ks = 0; ks < 2; ks++)
      w1f[ks] = w1p[(ks * 16 + wave) * 64 + lane];
    short8 w2f[8];
    #pragma unroll
    for (int ks = 0; ks < 8; ks++)
      w2f[ks] = w2p[(ks * 16 + wave) * 64 + lane];

    // W3 fragments in registers (waves 0-3 only; proven in round 2)
    short8 w3f[8];
    if (wave < 4) {
      const short8* w3p = (const short8*)(wsb + 81920);
      #pragma unroll
      for (int ks = 0; ks < 8; ks++)
        w3f[ks] = w3p[(ks * 4 + w3i) * 64 + lane];
    }

    if (bij == 0 && wave < 4) {
      // init private y slice from x and publish z_0 = y as bf16 A-frags
      yc = *(const f32x4*)(x + (row0 + cl) * 64 + dl3);
      uint2 pv;
      pv.x = pk2(yc[0], yc[1]);
      pv.y = pk2(yc[2], yc[3]);
      *(uint2*)(zA + zw) = pv;
    }
    // bij 1: y-frag was already published by the last stage-5 L3 below
    __syncthreads();

    for (int step = 0; step < NSTEPS; step++) {
      float stepf = (float)step;
      f32x4 kh[5];   // RK k-history, registers (waves 0-3; static indices only)
      #pragma unroll
      for (int s = 0; s < 6; s++) {
        float ts = (stepf + CT[s]) * hstep;

        // ---- layer 1: h1 = tanh(W1^T z_s + b1 + t*W1t), K=64
        {
          short8 a0 = *(const short8*)(zA + zrb);
          short8 a1 = *(const short8*)(zA + zrb + 544);
          f32x4 acc;
          #pragma unroll
          for (int r = 0; r < 4; r++)
            acc[r] = __builtin_fmaf(ts, w1t4[r], b1c[r]);
          acc = __builtin_amdgcn_mfma_f32_16x16x32_bf16(w1f[0], a0, acc, 0, 0, 0);
          acc = __builtin_amdgcn_mfma_f32_16x16x32_bf16(w1f[1], a1, acc, 0, 0, 0);
          uint2 pv;
          pv.x = pk2(tanh_fast(acc[0]), tanh_fast(acc[1]));
          pv.y = pk2(tanh_fast(acc[2]), tanh_fast(acc[3]));
          *(uint2*)(h1A + hoff) = pv;
        }
        __syncthreads();

        // ---- layer 2: h2 = tanh(W2^T h1 + b2), K=256, 2 chains of 4
        {
          f32x4 accA = b2c;
          f32x4 accB; accB[0] = 0.f; accB[1] = 0.f; accB[2] = 0.f; accB[3] = 0.f;
          #pragma unroll
          for (int ks = 0; ks < 4; ks++) {
            short8 hb = ((const short8*)h1A)[ks * 64 + lane];
            accA = __builtin_amdgcn_mfma_f32_16x16x32_bf16(w2f[ks], hb, accA, 0, 0, 0);
          }
          #pragma unroll
          for (int ks = 4; ks < 8; ks++) {
            short8 hb = ((const short8*)h1A)[ks * 64 + lane];
            accB = __builtin_amdgcn_mfma_f32_16x16x32_bf16(w2f[ks], hb, accB, 0, 0, 0);
          }
          uint2 pv;
          pv.x = pk2(tanh_fast(accA[0] + accB[0]), tanh_fast(accA[1] + accB[1]));
          pv.y = pk2(tanh_fast(accA[2] + accB[2]), tanh_fast(accA[3] + accB[3]));
          *(uint2*)(h2A + hoff) = pv;
        }
        __syncthreads();

        // ---- layer 3 + RK bookkeeping, waves 0-3 only:
        // k_s = W3^T h2 + b3 (full K=256, W3 frags in registers, 4 short
        // chains); k-history in registers; emit z_{s+1} (or update y).
        if (wave < 4) {
          f32x4 accP = b3c;
          f32x4 accQ = {0.f, 0.f, 0.f, 0.f};
          f32x4 accR = {0.f, 0.f, 0.f, 0.f};
          f32x4 accS = {0.f, 0.f, 0.f, 0.f};
          #pragma unroll
          for (int ks = 0; ks < 8; ks += 4) {
            short8 hb0 = ((const short8*)h2A)[ks * 64 + lane];
            short8 hb1 = ((const short8*)h2A)[(ks + 1) * 64 + lane];
            short8 hb2 = ((const short8*)h2A)[(ks + 2) * 64 + lane];
            short8 hb3 = ((const short8*)h2A)[(ks + 3) * 64 + lane];
            accP = __builtin_amdgcn_mfma_f32_16x16x32_bf16(w3f[ks], hb0, accP, 0, 0, 0);
            accQ = __builtin_amdgcn_mfma_f32_16x16x32_bf16(w3f[ks + 1], hb1, accQ, 0, 0, 0);
            accR = __builtin_amdgcn_mfma_f32_16x16x32_bf16(w3f[ks + 2], hb2, accR, 0, 0, 0);
            accS = __builtin_amdgcn_mfma_f32_16x16x32_bf16(w3f[ks + 3], hb3, accS, 0, 0, 0);
          }
          f32x4 kc;
          #pragma unroll
          for (int r = 0; r < 4; r++)
            kc[r] = (accP[r] + accQ[r]) + (accR[r] + accS[r]);

          f32x4 z;
          if (s < 5) {
            kh[s] = kc;
            #pragma unroll
            for (int r = 0; r < 4; r++)
              z[r] = __builtin_fmaf(hstep * A2[s][s], kc[r], yc[r]);
            #pragma unroll
            for (int j = 0; j < 4; j++)
              if (j < s) {
                float a = hstep * A2[s][j];
                #pragma unroll
                for (int r = 0; r < 4; r++) z[r] = __builtin_fmaf(a, kh[j][r], z[r]);
              }
          } else {
            #pragma unroll
            for (int r = 0; r < 4; r++) {
              float d = BW0 * kh[0][r] + BW2 * kh[2][r] + BW3 * kh[3][r] +
                        BW4 * kh[4][r] + BW5 * kc[r];
              yc[r] += hstep * d;
              z[r] = yc[r];   // z_0 of the next step (or bijector) is y itself
            }
          }
          uint2 pv;
          pv.x = pk2(z[0], z[1]);
          pv.y = pk2(z[2], z[3]);
          *(uint2*)(zA + zw) = pv;
        }
        __syncthreads();
      } // stages
    } // steps
  } // bijectors

  if (wave < 4)
    *(f32x4*)(out + (row0 + cl) * 64 + dl3) = yc;
}

extern "C" void kernel_launch(void* const* d_in, const int* in_sizes, int n_in,
                              void* d_out, int out_size, void* d_ws, size_t ws_size,
                              hipStream_t stream) {
  (void)in_sizes; (void)n_in; (void)out_size; (void)ws_size;
  const float* x   = (const float*)d_in[0];
  const float* W1a = (const float*)d_in[1];
  const float* b1a = (const float*)d_in[2];
  const float* W2a = (const float*)d_in[3];
  const float* b2a = (const float*)d_in[4];
  const float* W3a = (const float*)d_in[5];
  const float* b3a = (const float*)d_in[6];
  const float* W1b = (const float*)d_in[7];
  const float* b1b = (const float*)d_in[8];
  const float* W2b = (const float*)d_in[9];
  const float* b2b = (const float*)d_in[10];
  const float* W3b = (const float*)d_in[11];
  const float* b3b = (const float*)d_in[12];
  unsigned short* ws = (unsigned short*)d_ws;
  float* out = (float*)d_out;

  hipLaunchKernelGGL(ffjord_setup, dim3(96), dim3(256), 0, stream,
                     W1a, W2a, W3a, W1b, W2b, W3b, ws);
  hipLaunchKernelGGL(ffjord_main, dim3(256), dim3(1024), 0, stream,
                     x, out, ws, W1a, b1a, b2a, b3a, W1b, b1b, b2b, b3b);
}